// Round 10
// baseline (98.407 us; speedup 1.0000x reference)
//
#include <hip/hip_runtime.h>
#include <hip/hip_bf16.h>

#define DIMC 512
#define SEQ 4096
#define M_TOK 16384
#define N_QKV 1536

typedef __bf16 bfv8 __attribute__((ext_vector_type(8)));
typedef float f32v4 __attribute__((ext_vector_type(4)));
typedef unsigned short u16v8 __attribute__((ext_vector_type(8)));

#define VMCNT(n) asm volatile("s_waitcnt vmcnt(" #n ")" ::: "memory")
#define LGKM0()  asm volatile("s_waitcnt lgkmcnt(0)" ::: "memory")

static __device__ __forceinline__ float bf2f(unsigned short u) {
    union { unsigned int i; float f; } x; x.i = ((unsigned int)u) << 16; return x.f;
}
static __device__ __forceinline__ unsigned short f2bf(float f) {
    union { float f; unsigned int i; } x; x.f = f;
    unsigned int r = x.i + 0x7FFFu + ((x.i >> 16) & 1u);
    return (unsigned short)(r >> 16);
}

static __device__ __forceinline__ void gload_lds16(const void* g, void* s) {
    __builtin_amdgcn_global_load_lds(
        (const __attribute__((address_space(1))) unsigned int*)g,
        (__attribute__((address_space(3))) unsigned int*)s, 16, 0, 0);
}

// ---------------- fp32 -> bf16 conversion (weights only) ----------------
#define NWQ8 (N_QKV * DIMC / 8)          // 98304
#define NWO8 (DIMC * DIMC / 8)           // 32768
__global__ __launch_bounds__(256) void cvt_w(
    const float* __restrict__ wq, const float* __restrict__ wo,
    unsigned short* __restrict__ wqb, unsigned short* __restrict__ wob)
{
    int i = blockIdx.x * 256 + threadIdx.x;
    const float* src; unsigned short* dst; int off;
    if (i < NWQ8) { src = wq; dst = wqb; off = i; }
    else          { src = wo; dst = wob; off = i - NWQ8; }
    const float4* p = (const float4*)src + (size_t)off * 2;
    float4 a = p[0], b = p[1];
    u16v8 o;
    o[0] = f2bf(a.x); o[1] = f2bf(a.y); o[2] = f2bf(a.z); o[3] = f2bf(a.w);
    o[4] = f2bf(b.x); o[5] = f2bf(b.y); o[6] = f2bf(b.z); o[7] = f2bf(b.w);
    *(u16v8*)(dst + (size_t)off * 8) = o;
}

// ---- qkv GEMM, fused fp32->bf16 A-staging, T14 with CORRECT 1-iter offset --
// C[M][N] = cvt(A_f32)[M][K] * B[N][K]^T + bias, bf16 out.
// Block 128x256, 512 thr / 8 waves (2Mx4N), 64x64/wave, BK=32, ring-3 LDS.
// Iter t: load A(t+3)->regNext; STAGE_B(t+2); ds_write A(t+2) from regCur
// (loaded at t-1, >=1 full iter in flight -> landed, no stall); frag reads(t);
// MFMA; VMCNT(4) = exactly the 4 VMEM ops issued this iter, so B(t+1) proven
// landed (FIFO audit, incl. tails). R9's bug was write-late-by-ZERO.
__global__ __launch_bounds__(512) void gemm_qkv_f32a(
    const float* __restrict__ A,           // [M][K] f32 (x)
    const unsigned short* __restrict__ B,  // [N][K] bf16 (Wq)
    const float* __restrict__ bias,        // [N]
    unsigned short* __restrict__ Cout,     // [M][N] bf16
    int M, int N, int K)
{
    __shared__ __align__(16) unsigned short As[3][128 * 32];   // 24KB
    __shared__ __align__(16) unsigned short Bs[3][256 * 32];   // 48KB
    const int tid  = threadIdx.x;
    const int lane = tid & 63;
    const int wid  = tid >> 6;
    const int wm   = wid >> 2;
    const int wn   = wid & 3;
    const int m0 = blockIdx.x * 128;
    const int n0 = blockIdx.y * 256;
    const int frow = lane & 15;
    const int fcol = (lane >> 4) * 8;
    const int NT = K >> 5;           // 16

    f32v4 acc[4][4] = {};

    // A staging mapping == frag-read mapping (2-way bank alias = free):
    // row = wid*16 + (lane&15), cols (lane>>4)*8 .. +8
    const int arow = wid * 16 + (lane & 15);
    const int ak0  = (lane >> 4) * 8;
    const float* aSrcF = A + (size_t)(m0 + arow) * K + ak0;
    const int aWidx = (arow * 32 + ak0) ^ (((arow >> 1) & 3) << 3);

    // B staging (R8-proven): inverse-swizzled global source + linear gload_lds
    const unsigned short* bSrc[2];
    #pragma unroll
    for (int r = 0; r < 2; ++r) {
        const int brow = r * 128 + (tid >> 2);
        const int bcol = ((tid & 3) * 8) ^ (((brow >> 1) & 3) << 3);
        bSrc[r] = B + (size_t)(n0 + brow) * K + bcol;
    }
    const int bDst = wid * 512;      // wave-uniform (+lane*16B by HW)

#define STAGE_B(kt, slot)                                                      \
    {                                                                          \
        gload_lds16(bSrc[0] + (kt) * 32, &Bs[slot][bDst]);                     \
        gload_lds16(bSrc[1] + (kt) * 32, &Bs[slot][4096 + bDst]);              \
    }
#define A_LOAD(kt, v0, v1)                                                     \
    { v0 = *(const float4*)(aSrcF + (kt) * 32);                                \
      v1 = *(const float4*)(aSrcF + (kt) * 32 + 4); }
#define A_WRITE(slot, v0, v1)                                                  \
    {                                                                          \
        u16v8 cv_;                                                             \
        cv_[0] = f2bf(v0.x); cv_[1] = f2bf(v0.y); cv_[2] = f2bf(v0.z);         \
        cv_[3] = f2bf(v0.w); cv_[4] = f2bf(v1.x); cv_[5] = f2bf(v1.y);         \
        cv_[6] = f2bf(v1.z); cv_[7] = f2bf(v1.w);                              \
        *(u16v8*)&As[slot][aWidx] = cv_;                                       \
    }

    float4 aC0, aC1, aN0, aN1, p00, p01, p10, p11;
    // prologue: tiles 0,1 -> LDS (A via regs, B via gload_lds); A(2) -> regs
    A_LOAD(0, p00, p01)
    A_LOAD(1, p10, p11)
    STAGE_B(0, 0)
    STAGE_B(1, 1)
    A_WRITE(0, p00, p01)             // waits its own loads (startup only)
    A_WRITE(1, p10, p11)
    A_LOAD(2, aC0, aC1)
    VMCNT(4);                        // B(0) landed (B1x2 + A2x2 may remain)
    LGKM0();
    __builtin_amdgcn_s_barrier();

    for (int t = 0; t < NT; ++t) {
        const int slot = t % 3;
        if (t + 3 < NT) A_LOAD(t + 3, aN0, aN1)
        if (t + 2 < NT) {
            STAGE_B(t + 2, (t + 2) % 3)
            A_WRITE((t + 2) % 3, aC0, aC1)   // regs from iter t-1: landed
        }
        bfv8 af[4], bf[4];
        #pragma unroll
        for (int i = 0; i < 4; ++i) {
            const int r = wm * 64 + i * 16 + frow;
            af[i] = *(const bfv8*)(&As[slot][r * 32 + (fcol ^ (((r >> 1) & 3) << 3))]);
        }
        #pragma unroll
        for (int j = 0; j < 4; ++j) {
            const int r = wn * 64 + j * 16 + frow;
            bf[j] = *(const bfv8*)(&Bs[slot][r * 32 + (fcol ^ (((r >> 1) & 3) << 3))]);
        }
        LGKM0(); __builtin_amdgcn_sched_barrier(0);
        #pragma unroll
        for (int i = 0; i < 4; ++i)
            #pragma unroll
            for (int j = 0; j < 4; ++j)
                acc[i][j] = __builtin_amdgcn_mfma_f32_16x16x32_bf16(
                    af[i], bf[j], acc[i][j], 0, 0, 0);
        if (t + 2 < NT) { VMCNT(4); } else { VMCNT(0); }
        __builtin_amdgcn_s_barrier();
        aC0 = aN0; aC1 = aN1;
    }
#undef STAGE_B
#undef A_LOAD
#undef A_WRITE

    // epilogue: D row=(lane>>4)*4+r, col=lane&15 (m89-verified, proven R2-R8)
    const int erow = (lane >> 4) * 4;
    const int ecol = lane & 15;
    #pragma unroll
    for (int j = 0; j < 4; ++j) {
        const int col = n0 + wn * 64 + j * 16 + ecol;
        const float bv = bias[col];
        #pragma unroll
        for (int i = 0; i < 4; ++i) {
            const int rbase = m0 + wm * 64 + i * 16 + erow;
            #pragma unroll
            for (int r = 0; r < 4; ++r)
                Cout[(size_t)(rbase + r) * N + col] = f2bf(acc[i][j][r] + bv);
        }
    }
}

// ---- out GEMM: NT MFMA, 128x256 block, BK=32, ring-3 (R8-proven) ----------
__global__ __launch_bounds__(512) void gemm_nt_r3(
    const unsigned short* __restrict__ A,  // [M][K] bf16
    const unsigned short* __restrict__ B,  // [N][K] bf16
    const float* __restrict__ bias,        // [N]
    float* __restrict__ Cout,              // [M][N] f32
    int M, int N, int K)
{
    __shared__ __align__(16) unsigned short As[3][128 * 32];
    __shared__ __align__(16) unsigned short Bs[3][256 * 32];
    const int tid  = threadIdx.x;
    const int lane = tid & 63;
    const int wid  = tid >> 6;
    const int wm   = wid >> 2;
    const int wn   = wid & 3;
    const int m0 = blockIdx.x * 128;
    const int n0 = blockIdx.y * 256;
    const int frow = lane & 15;
    const int fcol = (lane >> 4) * 8;
    const int NT = K >> 5;

    f32v4 acc[4][4] = {};

    const int arow = tid >> 2;
    const int acol = ((tid & 3) * 8) ^ (((arow >> 1) & 3) << 3);
    const unsigned short* aSrc = A + (size_t)(m0 + arow) * K + acol;
    const unsigned short* bSrc[2];
    #pragma unroll
    for (int r = 0; r < 2; ++r) {
        const int brow = r * 128 + (tid >> 2);
        const int bcol = ((tid & 3) * 8) ^ (((brow >> 1) & 3) << 3);
        bSrc[r] = B + (size_t)(n0 + brow) * K + bcol;
    }
    const int aDst = wid * 512;

#define STAGE(kt, slot)                                                        \
    {                                                                          \
        gload_lds16(aSrc + (kt) * 32, &As[slot][aDst]);                        \
        gload_lds16(bSrc[0] + (kt) * 32, &Bs[slot][aDst]);                     \
        gload_lds16(bSrc[1] + (kt) * 32, &Bs[slot][4096 + aDst]);              \
    }

    STAGE(0, 0)
    STAGE(1, 1)
    VMCNT(3);
    __builtin_amdgcn_s_barrier();

    for (int t = 0; t < NT; ++t) {
        const int slot = t % 3;
        bfv8 af[4], bf[4];
        #pragma unroll
        for (int i = 0; i < 4; ++i) {
            const int r = wm * 64 + i * 16 + frow;
            af[i] = *(const bfv8*)(&As[slot][r * 32 + (fcol ^ (((r >> 1) & 3) << 3))]);
        }
        #pragma unroll
        for (int j = 0; j < 4; ++j) {
            const int r = wn * 64 + j * 16 + frow;
            bf[j] = *(const bfv8*)(&Bs[slot][r * 32 + (fcol ^ (((r >> 1) & 3) << 3))]);
        }
        if (t + 2 < NT) STAGE(t + 2, (t + 2) % 3)
        LGKM0(); __builtin_amdgcn_sched_barrier(0);
        #pragma unroll
        for (int i = 0; i < 4; ++i)
            #pragma unroll
            for (int j = 0; j < 4; ++j)
                acc[i][j] = __builtin_amdgcn_mfma_f32_16x16x32_bf16(
                    af[i], bf[j], acc[i][j], 0, 0, 0);
        if (t + 2 < NT) { VMCNT(3); } else { VMCNT(0); }
        __builtin_amdgcn_s_barrier();
    }
#undef STAGE

    const int erow = (lane >> 4) * 4;
    const int ecol = lane & 15;
    #pragma unroll
    for (int j = 0; j < 4; ++j) {
        const int col = n0 + wn * 64 + j * 16 + ecol;
        const float bv = bias[col];
        #pragma unroll
        for (int i = 0; i < 4; ++i) {
            const int rbase = m0 + wm * 64 + i * 16 + erow;
            #pragma unroll
            for (int r = 0; r < 4; ++r)
                Cout[(size_t)(rbase + r) * N + col] = acc[i][j][r] + bv;
        }
    }
}

// ---------------- per-token 8x8 head-mix attention, LDS-free ----------------
__global__ __launch_bounds__(256) void attn_mix2(
    const unsigned short* __restrict__ Y1, // [16384][1536] bf16
    unsigned short* __restrict__ Y2)       // [16384][512]  bf16 (scrambled)
{
    const int tid  = threadIdx.x;
    const int tok  = blockIdx.x * 16 + (tid >> 4);
    const int l16  = tid & 15;
    const int h    = l16 >> 1;
    const int half = l16 & 1;
    const unsigned short* qkv = Y1 + (size_t)tok * N_QKV;

    float qf[32];
    #pragma unroll
    for (int c = 0; c < 4; ++c) {
        u16v8 v = *(const u16v8*)(qkv + h * 64 + half * 32 + c * 8);
        #pragma unroll
        for (int j = 0; j < 8; ++j) qf[c * 8 + j] = bf2f(v[j]);
    }
    float sc[8];
    #pragma unroll
    for (int g = 0; g < 8; ++g) {
        const unsigned short* kp = qkv + DIMC + g * 64 + half * 32;
        float a = 0.f;
        #pragma unroll
        for (int c = 0; c < 4; ++c) {
            u16v8 v = *(const u16v8*)(kp + c * 8);
            #pragma unroll
            for (int j = 0; j < 8; ++j) a = fmaf(qf[c * 8 + j], bf2f(v[j]), a);
        }
        a += __shfl_xor(a, 1);
        sc[g] = a * 0.125f;
    }
    float mx = sc[0];
    #pragma unroll
    for (int g = 1; g < 8; ++g) mx = fmaxf(mx, sc[g]);
    float sum = 0.f;
    #pragma unroll
    for (int g = 0; g < 8; ++g) { sc[g] = __expf(sc[g] - mx); sum += sc[g]; }
    const float inv = 1.f / sum;
    #pragma unroll
    for (int g = 0; g < 8; ++g) sc[g] *= inv;

    float o[32] = {};
    #pragma unroll
    for (int g = 0; g < 8; ++g) {
        const unsigned short* vp = qkv + 2 * DIMC + g * 64 + half * 32;
        #pragma unroll
        for (int c = 0; c < 4; ++c) {
            u16v8 v = *(const u16v8*)(vp + c * 8);
            #pragma unroll
            for (int j = 0; j < 8; ++j) o[c * 8 + j] = fmaf(sc[g], bf2f(v[j]), o[c * 8 + j]);
        }
    }
    const int n = tok & (SEQ - 1);
    const int b = tok >> 12;
    const size_t drow = (size_t)b * SEQ + h * 512 + (n >> 3);
    unsigned short* dst = Y2 + drow * DIMC + ((n & 7) << 6) + half * 32;
    #pragma unroll
    for (int c = 0; c < 4; ++c) {
        u16v8 ov;
        #pragma unroll
        for (int j = 0; j < 8; ++j) ov[j] = f2bf(o[c * 8 + j]);
        *(u16v8*)(dst + c * 8) = ov;
    }
}

extern "C" void kernel_launch(void* const* d_in, const int* in_sizes, int n_in,
                              void* d_out, int out_size, void* d_ws, size_t ws_size,
                              hipStream_t stream) {
    const float* x     = (const float*)d_in[0];
    const float* qkv_w = (const float*)d_in[1];
    const float* qkv_b = (const float*)d_in[2];
    const float* out_w = (const float*)d_in[3];
    const float* out_b = (const float*)d_in[4];
    float* out = (float*)d_out;

    unsigned short* Y1 = (unsigned short*)d_ws;            // 50.3 MB
    unsigned short* Y2 = Y1 + (size_t)M_TOK * N_QKV;       // 16.8 MB
    unsigned short* Wq = Y2 + (size_t)M_TOK * DIMC;        // 1.6 MB
    unsigned short* Wo = Wq + (size_t)N_QKV * DIMC;        // 0.5 MB

    cvt_w<<<(NWQ8 + NWO8) / 256, 256, 0, stream>>>(qkv_w, out_w, Wq, Wo);

    gemm_qkv_f32a<<<dim3(M_TOK / 128, N_QKV / 256), 512, 0, stream>>>(
        x, Wq, qkv_b, Y1, M_TOK, N_QKV, DIMC);

    attn_mix2<<<M_TOK / 16, 256, 0, stream>>>(Y1, Y2);

    gemm_nt_r3<<<dim3(M_TOK / 128, DIMC / 256), 512, 0, stream>>>(
        Y2, Wo, out_b, out, M_TOK, DIMC, DIMC);
}

// Round 11
// 86.892 us; speedup vs baseline: 1.1325x; 1.1325x over previous
//
#include <hip/hip_runtime.h>
#include <hip/hip_bf16.h>

#define DIMC 512
#define SEQ 4096
#define M_TOK 16384
#define N_QKV 1536

typedef __bf16 bfv8 __attribute__((ext_vector_type(8)));
typedef float f32v4 __attribute__((ext_vector_type(4)));
typedef unsigned short u16v8 __attribute__((ext_vector_type(8)));

#define VMCNT(n) asm volatile("s_waitcnt vmcnt(" #n ")" ::: "memory")
#define LGKM0()  asm volatile("s_waitcnt lgkmcnt(0)" ::: "memory")

static __device__ __forceinline__ float bf2f(unsigned short u) {
    union { unsigned int i; float f; } x; x.i = ((unsigned int)u) << 16; return x.f;
}
static __device__ __forceinline__ unsigned short f2bf(float f) {
    union { float f; unsigned int i; } x; x.f = f;
    unsigned int r = x.i + 0x7FFFu + ((x.i >> 16) & 1u);
    return (unsigned short)(r >> 16);
}

static __device__ __forceinline__ void gload_lds16(const void* g, void* s) {
    __builtin_amdgcn_global_load_lds(
        (const __attribute__((address_space(1))) unsigned int*)g,
        (__attribute__((address_space(3))) unsigned int*)s, 16, 0, 0);
}

// ---------------- fp32 -> bf16 conversion (weights only) ----------------
#define NWQ8 (N_QKV * DIMC / 8)          // 98304
#define NWO8 (DIMC * DIMC / 8)           // 32768
__global__ __launch_bounds__(256) void cvt_w(
    const float* __restrict__ wq, const float* __restrict__ wo,
    unsigned short* __restrict__ wqb, unsigned short* __restrict__ wob)
{
    int i = blockIdx.x * 256 + threadIdx.x;
    const float* src; unsigned short* dst; int off;
    if (i < NWQ8) { src = wq; dst = wqb; off = i; }
    else          { src = wo; dst = wob; off = i - NWQ8; }
    const float4* p = (const float4*)src + (size_t)off * 2;
    float4 a = p[0], b = p[1];
    u16v8 o;
    o[0] = f2bf(a.x); o[1] = f2bf(a.y); o[2] = f2bf(a.z); o[3] = f2bf(a.w);
    o[4] = f2bf(b.x); o[5] = f2bf(b.y); o[6] = f2bf(b.z); o[7] = f2bf(b.w);
    *(u16v8*)(dst + (size_t)off * 8) = o;
}

// ---- qkv GEMM: fp32 A staged DIRECTLY via gload_lds (no x pre-conversion) --
// C[M][N] = cvt(A_f32)[M][K] * B[N][K]^T + bias, bf16 out.
// Block 128x256, 512 thr / 8 waves (2Mx4N), 64x64/wave, BK=32, ring-3 LDS.
// AsF fp32 [3][128][32] (48KB), swizzle g ^= (row&7) on 16B granules
// (byte ^= (row&7)<<4, G4) inverse-applied to global source (rule 21);
// frag read = 2x ds_read_b128 f32 + hardware (__bf16) cvt (RNE).
// B path / schedule / vmcnt identical to R8 (proven 40us): 4 VMEM ops per
// tile, stage t+2 at iter t, VMCNT(4) steady, VMCNT(0) tail.
__global__ __launch_bounds__(512) void gemm_qkv_f32a(
    const float* __restrict__ A,           // [M][K] f32 (x)
    const unsigned short* __restrict__ B,  // [N][K] bf16 (Wq)
    const float* __restrict__ bias,        // [N]
    unsigned short* __restrict__ Cout,     // [M][N] bf16
    int M, int N, int K)
{
    __shared__ __align__(16) float          AsF[3][128 * 32];   // 48KB
    __shared__ __align__(16) unsigned short Bs[3][256 * 32];    // 48KB
    const int tid  = threadIdx.x;
    const int lane = tid & 63;
    const int wid  = tid >> 6;
    const int wm   = wid >> 2;
    const int wn   = wid & 3;
    const int m0 = blockIdx.x * 128;
    const int n0 = blockIdx.y * 256;
    const int frow = lane & 15;
    const int fcol = (lane >> 4) * 8;      // bf16 B frag col
    const int NT = K >> 5;                 // 16

    f32v4 acc[4][4] = {};

    // A staging: 2 calls; thread covers 16B granule g=tid&7 of row (s*512+tid)/8
    const float* aSrcG[2];
    #pragma unroll
    for (int s = 0; s < 2; ++s) {
        const int row = (s * 512 + tid) >> 3;
        const int g   = tid & 7;
        aSrcG[s] = A + (size_t)(m0 + row) * K + ((g ^ (row & 7)) << 2);
    }
    // B staging (R8-proven): inverse-swizzled source + linear gload_lds
    const unsigned short* bSrc[2];
    #pragma unroll
    for (int r = 0; r < 2; ++r) {
        const int brow = r * 128 + (tid >> 2);
        const int bcol = ((tid & 3) * 8) ^ (((brow >> 1) & 3) << 3);
        bSrc[r] = B + (size_t)(n0 + brow) * K + bcol;
    }
    const int bDst = wid * 512;            // u16 elems (+lane*16B by HW)
    const int aDstF = wid * 256;           // f32 elems (+lane*16B by HW)

#define STAGE(kt, slot)                                                        \
    {                                                                          \
        gload_lds16(aSrcG[0] + (kt) * 32, &AsF[slot][aDstF]);                  \
        gload_lds16(aSrcG[1] + (kt) * 32, &AsF[slot][2048 + aDstF]);           \
        gload_lds16(bSrc[0] + (kt) * 32, &Bs[slot][bDst]);                     \
        gload_lds16(bSrc[1] + (kt) * 32, &Bs[slot][4096 + bDst]);              \
    }

    STAGE(0, 0)
    STAGE(1, 1)
    VMCNT(4);                      // tile-0 landed (tile-1's 4 remain)
    __builtin_amdgcn_s_barrier();

    for (int t = 0; t < NT; ++t) {
        const int slot = t % 3;
        // A frags: 2x b128 f32 per frag, swizzled granule, then cvt to bf16
        f32v4 alo[4], ahi[4];
        #pragma unroll
        for (int i = 0; i < 4; ++i) {
            const int r = wm * 64 + i * 16 + frow;
            const int m = r & 7;
            const int g0 = (lane >> 4) * 2;
            alo[i] = *(const f32v4*)(&AsF[slot][r * 32 + ((g0 ^ m) << 2)]);
            ahi[i] = *(const f32v4*)(&AsF[slot][r * 32 + (((g0 + 1) ^ m) << 2)]);
        }
        bfv8 bf[4];
        #pragma unroll
        for (int j = 0; j < 4; ++j) {
            const int r = wn * 64 + j * 16 + frow;
            bf[j] = *(const bfv8*)(&Bs[slot][r * 32 + (fcol ^ (((r >> 1) & 3) << 3))]);
        }
        if (t + 2 < NT) STAGE(t + 2, (t + 2) % 3)
        LGKM0(); __builtin_amdgcn_sched_barrier(0);
        bfv8 af[4];
        #pragma unroll
        for (int i = 0; i < 4; ++i) {
            bfv8 v;
            v[0] = (__bf16)alo[i][0]; v[1] = (__bf16)alo[i][1];
            v[2] = (__bf16)alo[i][2]; v[3] = (__bf16)alo[i][3];
            v[4] = (__bf16)ahi[i][0]; v[5] = (__bf16)ahi[i][1];
            v[6] = (__bf16)ahi[i][2]; v[7] = (__bf16)ahi[i][3];
            af[i] = v;
        }
        #pragma unroll
        for (int i = 0; i < 4; ++i)
            #pragma unroll
            for (int j = 0; j < 4; ++j)
                acc[i][j] = __builtin_amdgcn_mfma_f32_16x16x32_bf16(
                    af[i], bf[j], acc[i][j], 0, 0, 0);
        if (t + 2 < NT) { VMCNT(4); } else { VMCNT(0); }
        __builtin_amdgcn_s_barrier();
    }
#undef STAGE

    // epilogue: D row=(lane>>4)*4+r, col=lane&15 (m89-verified, proven R2-R8)
    const int erow = (lane >> 4) * 4;
    const int ecol = lane & 15;
    #pragma unroll
    for (int j = 0; j < 4; ++j) {
        const int col = n0 + wn * 64 + j * 16 + ecol;
        const float bv = bias[col];
        #pragma unroll
        for (int i = 0; i < 4; ++i) {
            const int rbase = m0 + wm * 64 + i * 16 + erow;
            #pragma unroll
            for (int r = 0; r < 4; ++r)
                Cout[(size_t)(rbase + r) * N + col] = f2bf(acc[i][j][r] + bv);
        }
    }
}

// ---- out GEMM: NT MFMA, 128x256 block, BK=32, ring-3 (R8-proven) ----------
__global__ __launch_bounds__(512) void gemm_nt_r3(
    const unsigned short* __restrict__ A,  // [M][K] bf16
    const unsigned short* __restrict__ B,  // [N][K] bf16
    const float* __restrict__ bias,        // [N]
    float* __restrict__ Cout,              // [M][N] f32
    int M, int N, int K)
{
    __shared__ __align__(16) unsigned short As[3][128 * 32];
    __shared__ __align__(16) unsigned short Bs[3][256 * 32];
    const int tid  = threadIdx.x;
    const int lane = tid & 63;
    const int wid  = tid >> 6;
    const int wm   = wid >> 2;
    const int wn   = wid & 3;
    const int m0 = blockIdx.x * 128;
    const int n0 = blockIdx.y * 256;
    const int frow = lane & 15;
    const int fcol = (lane >> 4) * 8;
    const int NT = K >> 5;

    f32v4 acc[4][4] = {};

    const int arow = tid >> 2;
    const int acol = ((tid & 3) * 8) ^ (((arow >> 1) & 3) << 3);
    const unsigned short* aSrc = A + (size_t)(m0 + arow) * K + acol;
    const unsigned short* bSrc[2];
    #pragma unroll
    for (int r = 0; r < 2; ++r) {
        const int brow = r * 128 + (tid >> 2);
        const int bcol = ((tid & 3) * 8) ^ (((brow >> 1) & 3) << 3);
        bSrc[r] = B + (size_t)(n0 + brow) * K + bcol;
    }
    const int aDst = wid * 512;

#define STAGE(kt, slot)                                                        \
    {                                                                          \
        gload_lds16(aSrc + (kt) * 32, &As[slot][aDst]);                        \
        gload_lds16(bSrc[0] + (kt) * 32, &Bs[slot][aDst]);                     \
        gload_lds16(bSrc[1] + (kt) * 32, &Bs[slot][4096 + aDst]);              \
    }

    STAGE(0, 0)
    STAGE(1, 1)
    VMCNT(3);
    __builtin_amdgcn_s_barrier();

    for (int t = 0; t < NT; ++t) {
        const int slot = t % 3;
        bfv8 af[4], bf[4];
        #pragma unroll
        for (int i = 0; i < 4; ++i) {
            const int r = wm * 64 + i * 16 + frow;
            af[i] = *(const bfv8*)(&As[slot][r * 32 + (fcol ^ (((r >> 1) & 3) << 3))]);
        }
        #pragma unroll
        for (int j = 0; j < 4; ++j) {
            const int r = wn * 64 + j * 16 + frow;
            bf[j] = *(const bfv8*)(&Bs[slot][r * 32 + (fcol ^ (((r >> 1) & 3) << 3))]);
        }
        if (t + 2 < NT) STAGE(t + 2, (t + 2) % 3)
        LGKM0(); __builtin_amdgcn_sched_barrier(0);
        #pragma unroll
        for (int i = 0; i < 4; ++i)
            #pragma unroll
            for (int j = 0; j < 4; ++j)
                acc[i][j] = __builtin_amdgcn_mfma_f32_16x16x32_bf16(
                    af[i], bf[j], acc[i][j], 0, 0, 0);
        if (t + 2 < NT) { VMCNT(3); } else { VMCNT(0); }
        __builtin_amdgcn_s_barrier();
    }
#undef STAGE

    const int erow = (lane >> 4) * 4;
    const int ecol = lane & 15;
    #pragma unroll
    for (int j = 0; j < 4; ++j) {
        const int col = n0 + wn * 64 + j * 16 + ecol;
        const float bv = bias[col];
        #pragma unroll
        for (int i = 0; i < 4; ++i) {
            const int rbase = m0 + wm * 64 + i * 16 + erow;
            #pragma unroll
            for (int r = 0; r < 4; ++r)
                Cout[(size_t)(rbase + r) * N + col] = acc[i][j][r] + bv;
        }
    }
}

// ---------------- per-token 8x8 head-mix attention, LDS-free ----------------
__global__ __launch_bounds__(256) void attn_mix2(
    const unsigned short* __restrict__ Y1, // [16384][1536] bf16
    unsigned short* __restrict__ Y2)       // [16384][512]  bf16 (scrambled)
{
    const int tid  = threadIdx.x;
    const int tok  = blockIdx.x * 16 + (tid >> 4);
    const int l16  = tid & 15;
    const int h    = l16 >> 1;
    const int half = l16 & 1;
    const unsigned short* qkv = Y1 + (size_t)tok * N_QKV;

    float qf[32];
    #pragma unroll
    for (int c = 0; c < 4; ++c) {
        u16v8 v = *(const u16v8*)(qkv + h * 64 + half * 32 + c * 8);
        #pragma unroll
        for (int j = 0; j < 8; ++j) qf[c * 8 + j] = bf2f(v[j]);
    }
    float sc[8];
    #pragma unroll
    for (int g = 0; g < 8; ++g) {
        const unsigned short* kp = qkv + DIMC + g * 64 + half * 32;
        float a = 0.f;
        #pragma unroll
        for (int c = 0; c < 4; ++c) {
            u16v8 v = *(const u16v8*)(kp + c * 8);
            #pragma unroll
            for (int j = 0; j < 8; ++j) a = fmaf(qf[c * 8 + j], bf2f(v[j]), a);
        }
        a += __shfl_xor(a, 1);
        sc[g] = a * 0.125f;
    }
    float mx = sc[0];
    #pragma unroll
    for (int g = 1; g < 8; ++g) mx = fmaxf(mx, sc[g]);
    float sum = 0.f;
    #pragma unroll
    for (int g = 0; g < 8; ++g) { sc[g] = __expf(sc[g] - mx); sum += sc[g]; }
    const float inv = 1.f / sum;
    #pragma unroll
    for (int g = 0; g < 8; ++g) sc[g] *= inv;

    float o[32] = {};
    #pragma unroll
    for (int g = 0; g < 8; ++g) {
        const unsigned short* vp = qkv + 2 * DIMC + g * 64 + half * 32;
        #pragma unroll
        for (int c = 0; c < 4; ++c) {
            u16v8 v = *(const u16v8*)(vp + c * 8);
            #pragma unroll
            for (int j = 0; j < 8; ++j) o[c * 8 + j] = fmaf(sc[g], bf2f(v[j]), o[c * 8 + j]);
        }
    }
    const int n = tok & (SEQ - 1);
    const int b = tok >> 12;
    const size_t drow = (size_t)b * SEQ + h * 512 + (n >> 3);
    unsigned short* dst = Y2 + drow * DIMC + ((n & 7) << 6) + half * 32;
    #pragma unroll
    for (int c = 0; c < 4; ++c) {
        u16v8 ov;
        #pragma unroll
        for (int j = 0; j < 8; ++j) ov[j] = f2bf(o[c * 8 + j]);
        *(u16v8*)(dst + c * 8) = ov;
    }
}

extern "C" void kernel_launch(void* const* d_in, const int* in_sizes, int n_in,
                              void* d_out, int out_size, void* d_ws, size_t ws_size,
                              hipStream_t stream) {
    const float* x     = (const float*)d_in[0];
    const float* qkv_w = (const float*)d_in[1];
    const float* qkv_b = (const float*)d_in[2];
    const float* out_w = (const float*)d_in[3];
    const float* out_b = (const float*)d_in[4];
    float* out = (float*)d_out;

    unsigned short* Y1 = (unsigned short*)d_ws;            // 50.3 MB
    unsigned short* Y2 = Y1 + (size_t)M_TOK * N_QKV;       // 16.8 MB
    unsigned short* Wq = Y2 + (size_t)M_TOK * DIMC;        // 1.6 MB
    unsigned short* Wo = Wq + (size_t)N_QKV * DIMC;        // 0.5 MB

    cvt_w<<<(NWQ8 + NWO8) / 256, 256, 0, stream>>>(qkv_w, out_w, Wq, Wo);

    gemm_qkv_f32a<<<dim3(M_TOK / 128, N_QKV / 256), 512, 0, stream>>>(
        x, Wq, qkv_b, Y1, M_TOK, N_QKV, DIMC);

    attn_mix2<<<M_TOK / 16, 256, 0, stream>>>(Y1, Y2);

    gemm_nt_r3<<<dim3(M_TOK / 128, DIMC / 256), 512, 0, stream>>>(
        Y2, Wo, out_b, out, M_TOK, DIMC, DIMC);
}

// Round 12
// 81.565 us; speedup vs baseline: 1.2065x; 1.0653x over previous
//
#include <hip/hip_runtime.h>
#include <hip/hip_bf16.h>

#define DIMC 512
#define SEQ 4096
#define M_TOK 16384
#define N_QKV 1536

typedef __bf16 bfv8 __attribute__((ext_vector_type(8)));
typedef float f32v4 __attribute__((ext_vector_type(4)));
typedef unsigned short u16v8 __attribute__((ext_vector_type(8)));

#define VMCNT(n) asm volatile("s_waitcnt vmcnt(" #n ")" ::: "memory")
#define LGKM0()  asm volatile("s_waitcnt lgkmcnt(0)" ::: "memory")

static __device__ __forceinline__ float bf2f(unsigned short u) {
    union { unsigned int i; float f; } x; x.i = ((unsigned int)u) << 16; return x.f;
}
static __device__ __forceinline__ unsigned short f2bf(float f) {
    union { float f; unsigned int i; } x; x.f = f;
    unsigned int r = x.i + 0x7FFFu + ((x.i >> 16) & 1u);
    return (unsigned short)(r >> 16);
}

static __device__ __forceinline__ void gload_lds16(const void* g, void* s) {
    __builtin_amdgcn_global_load_lds(
        (const __attribute__((address_space(1))) unsigned int*)g,
        (__attribute__((address_space(3))) unsigned int*)s, 16, 0, 0);
}

// ---------------- merged fp32 -> bf16 conversion (x, qkv_w, out_w) ---------
#define NX8  (M_TOK * DIMC / 8)          // 1048576
#define NWQ8 (N_QKV * DIMC / 8)          // 98304
#define NWO8 (DIMC * DIMC / 8)           // 32768
__global__ __launch_bounds__(256) void cvt_all(
    const float* __restrict__ x,  const float* __restrict__ wq,
    const float* __restrict__ wo, unsigned short* __restrict__ xb,
    unsigned short* __restrict__ wqb, unsigned short* __restrict__ wob)
{
    int i = blockIdx.x * 256 + threadIdx.x;
    const float* src; unsigned short* dst; int off;
    if (i < NX8)             { src = x;  dst = xb;  off = i; }
    else if (i < NX8 + NWQ8) { src = wq; dst = wqb; off = i - NX8; }
    else                     { src = wo; dst = wob; off = i - NX8 - NWQ8; }
    const float4* p = (const float4*)src + (size_t)off * 2;
    float4 a = p[0], b = p[1];
    u16v8 o;
    o[0] = f2bf(a.x); o[1] = f2bf(a.y); o[2] = f2bf(a.z); o[3] = f2bf(a.w);
    o[4] = f2bf(b.x); o[5] = f2bf(b.y); o[6] = f2bf(b.z); o[7] = f2bf(b.w);
    *(u16v8*)(dst + (size_t)off * 8) = o;
}

// ---- NT MFMA GEMM, 128x256 block, BK=32, RING-3 LDS + counted vmcnt -------
// C[M][N] = A[M][K]*B[N][K]^T + bias. 512 thr / 8 waves (2Mx4N), 64x64/wave.
// EXACT R8 structure (best measured: qkv 40.0us, conflicts 0) + T5 setprio
// around the MFMA cluster (structure-conditional hint; removable).
template<bool OUT_BF16>
__global__ __launch_bounds__(512) void gemm_nt_r3(
    const unsigned short* __restrict__ A,  // [M][K] bf16
    const unsigned short* __restrict__ B,  // [N][K] bf16
    const float* __restrict__ bias,        // [N]
    void* __restrict__ Cout,
    int M, int N, int K)
{
    __shared__ __align__(16) unsigned short As[3][128 * 32];   // 24KB
    __shared__ __align__(16) unsigned short Bs[3][256 * 32];   // 48KB
    const int tid  = threadIdx.x;
    const int lane = tid & 63;
    const int wid  = tid >> 6;       // 0..7
    const int wm   = wid >> 2;       // 0..1 -> rows [wm*64,+64)
    const int wn   = wid & 3;        // 0..3 -> cols [wn*64,+64)
    const int m0 = blockIdx.x * 128;
    const int n0 = blockIdx.y * 256;
    const int frow = lane & 15;
    const int fcol = (lane >> 4) * 8;
    const int NT = K >> 5;           // 16 K-tiles

    f32v4 acc[4][4] = {};

    // staging addresses (inverse-swizzled global source, rule 21)
    const int arow = tid >> 2;
    const int acol = ((tid & 3) * 8) ^ (((arow >> 1) & 3) << 3);
    const unsigned short* aSrc = A + (size_t)(m0 + arow) * K + acol;
    const unsigned short* bSrc[2];
    #pragma unroll
    for (int r = 0; r < 2; ++r) {
        const int brow = r * 128 + (tid >> 2);
        const int bcol = ((tid & 3) * 8) ^ (((brow >> 1) & 3) << 3);
        bSrc[r] = B + (size_t)(n0 + brow) * K + bcol;
    }
    const int aDst = wid * 512;            // wave-uniform (+lane*16B by HW)

#define STAGE(kt, slot)                                                        \
    {                                                                          \
        gload_lds16(aSrc + (kt) * 32, &As[slot][aDst]);                        \
        gload_lds16(bSrc[0] + (kt) * 32, &Bs[slot][aDst]);                     \
        gload_lds16(bSrc[1] + (kt) * 32, &Bs[slot][4096 + aDst]);              \
    }

    STAGE(0, 0)
    STAGE(1, 1)
    VMCNT(3);                      // tile-0 landed (only tile-1's 3 remain)
    __builtin_amdgcn_s_barrier();

    for (int t = 0; t < NT; ++t) {
        const int slot = t % 3;
        bfv8 af[4], bf[4];
        #pragma unroll
        for (int i = 0; i < 4; ++i) {
            const int r = wm * 64 + i * 16 + frow;
            af[i] = *(const bfv8*)(&As[slot][r * 32 + (fcol ^ (((r >> 1) & 3) << 3))]);
        }
        #pragma unroll
        for (int j = 0; j < 4; ++j) {
            const int r = wn * 64 + j * 16 + frow;
            bf[j] = *(const bfv8*)(&Bs[slot][r * 32 + (fcol ^ (((r >> 1) & 3) << 3))]);
        }
        if (t + 2 < NT) {
            const int ws = (t + 2) % 3;
            STAGE(t + 2, ws)
        }
        LGKM0(); __builtin_amdgcn_sched_barrier(0);
        __builtin_amdgcn_s_setprio(1);
        #pragma unroll
        for (int i = 0; i < 4; ++i)
            #pragma unroll
            for (int j = 0; j < 4; ++j)
                acc[i][j] = __builtin_amdgcn_mfma_f32_16x16x32_bf16(
                    af[i], bf[j], acc[i][j], 0, 0, 0);
        __builtin_amdgcn_s_setprio(0);
        if (t + 2 < NT) { VMCNT(3); } else { VMCNT(0); }
        __builtin_amdgcn_s_barrier();
    }
#undef STAGE

    // epilogue: D row=(lane>>4)*4+r, col=lane&15 (m89-verified, R2..R8-proven)
    const int erow = (lane >> 4) * 4;
    const int ecol = lane & 15;
    #pragma unroll
    for (int j = 0; j < 4; ++j) {
        const int col = n0 + wn * 64 + j * 16 + ecol;
        const float bv = bias[col];
        #pragma unroll
        for (int i = 0; i < 4; ++i) {
            const int rbase = m0 + wm * 64 + i * 16 + erow;
            #pragma unroll
            for (int r = 0; r < 4; ++r) {
                const float v = acc[i][j][r] + bv;
                if constexpr (OUT_BF16)
                    ((unsigned short*)Cout)[(size_t)(rbase + r) * N + col] = f2bf(v);
                else
                    ((float*)Cout)[(size_t)(rbase + r) * N + col] = v;
            }
        }
    }
}

// ---------------- per-token 8x8 head-mix attention, LDS-free ----------------
// 16 lanes per token: lane16 = h*2 + half (half = 32-dim split).
// Writes Y2 scrambled: y[b][h*512 + (n>>3)][(n&7)*64 + d].
__global__ __launch_bounds__(256) void attn_mix2(
    const unsigned short* __restrict__ Y1, // [16384][1536] bf16
    unsigned short* __restrict__ Y2)       // [16384][512]  bf16 (scrambled)
{
    const int tid  = threadIdx.x;
    const int tok  = blockIdx.x * 16 + (tid >> 4);
    const int l16  = tid & 15;
    const int h    = l16 >> 1;
    const int half = l16 & 1;
    const unsigned short* qkv = Y1 + (size_t)tok * N_QKV;

    float qf[32];
    #pragma unroll
    for (int c = 0; c < 4; ++c) {
        u16v8 v = *(const u16v8*)(qkv + h * 64 + half * 32 + c * 8);
        #pragma unroll
        for (int j = 0; j < 8; ++j) qf[c * 8 + j] = bf2f(v[j]);
    }
    float sc[8];
    #pragma unroll
    for (int g = 0; g < 8; ++g) {
        const unsigned short* kp = qkv + DIMC + g * 64 + half * 32;
        float a = 0.f;
        #pragma unroll
        for (int c = 0; c < 4; ++c) {
            u16v8 v = *(const u16v8*)(kp + c * 8);
            #pragma unroll
            for (int j = 0; j < 8; ++j) a = fmaf(qf[c * 8 + j], bf2f(v[j]), a);
        }
        a += __shfl_xor(a, 1);       // combine the two 32-dim halves
        sc[g] = a * 0.125f;
    }
    float mx = sc[0];
    #pragma unroll
    for (int g = 1; g < 8; ++g) mx = fmaxf(mx, sc[g]);
    float sum = 0.f;
    #pragma unroll
    for (int g = 0; g < 8; ++g) { sc[g] = __expf(sc[g] - mx); sum += sc[g]; }
    const float inv = 1.f / sum;
    #pragma unroll
    for (int g = 0; g < 8; ++g) sc[g] *= inv;

    float o[32] = {};
    #pragma unroll
    for (int g = 0; g < 8; ++g) {
        const unsigned short* vp = qkv + 2 * DIMC + g * 64 + half * 32;
        #pragma unroll
        for (int c = 0; c < 4; ++c) {
            u16v8 v = *(const u16v8*)(vp + c * 8);
            #pragma unroll
            for (int j = 0; j < 8; ++j) o[c * 8 + j] = fmaf(sc[g], bf2f(v[j]), o[c * 8 + j]);
        }
    }
    const int n = tok & (SEQ - 1);
    const int b = tok >> 12;
    const size_t drow = (size_t)b * SEQ + h * 512 + (n >> 3);
    unsigned short* dst = Y2 + drow * DIMC + ((n & 7) << 6) + half * 32;
    #pragma unroll
    for (int c = 0; c < 4; ++c) {
        u16v8 ov;
        #pragma unroll
        for (int j = 0; j < 8; ++j) ov[j] = f2bf(o[c * 8 + j]);
        *(u16v8*)(dst + c * 8) = ov;
    }
}

extern "C" void kernel_launch(void* const* d_in, const int* in_sizes, int n_in,
                              void* d_out, int out_size, void* d_ws, size_t ws_size,
                              hipStream_t stream) {
    const float* x     = (const float*)d_in[0];
    const float* qkv_w = (const float*)d_in[1];
    const float* qkv_b = (const float*)d_in[2];
    const float* out_w = (const float*)d_in[3];
    const float* out_b = (const float*)d_in[4];
    float* out = (float*)d_out;

    unsigned short* Y1 = (unsigned short*)d_ws;            // 50.3 MB
    unsigned short* Xb = Y1 + (size_t)M_TOK * N_QKV;       // 16.8 MB
    unsigned short* Y2 = Xb;   // overlay: Xb dead before attn_mix2 writes Y2
    unsigned short* Wq = Xb + (size_t)M_TOK * DIMC;
    unsigned short* Wo = Wq + (size_t)N_QKV * DIMC;

    cvt_all<<<(NX8 + NWQ8 + NWO8) / 256, 256, 0, stream>>>(x, qkv_w, out_w, Xb, Wq, Wo);

    gemm_nt_r3<true><<<dim3(M_TOK / 128, N_QKV / 256), 512, 0, stream>>>(
        Xb, Wq, qkv_b, Y1, M_TOK, N_QKV, DIMC);

    attn_mix2<<<M_TOK / 16, 256, 0, stream>>>(Y1, Y2);

    gemm_nt_r3<false><<<dim3(M_TOK / 128, DIMC / 256), 512, 0, stream>>>(
        Y2, Wo, out_b, out, M_TOK, DIMC, DIMC);
}

// Round 13
// 81.279 us; speedup vs baseline: 1.2107x; 1.0035x over previous
//
#include <hip/hip_runtime.h>
#include <hip/hip_bf16.h>

#define DIMC 512
#define SEQ 4096
#define M_TOK 16384
#define N_QKV 1536

typedef __bf16 bfv8 __attribute__((ext_vector_type(8)));
typedef float f32v4 __attribute__((ext_vector_type(4)));
typedef unsigned short u16v8 __attribute__((ext_vector_type(8)));

#define VMCNT(n) asm volatile("s_waitcnt vmcnt(" #n ")" ::: "memory")

static __device__ __forceinline__ float bf2f(unsigned short u) {
    union { unsigned int i; float f; } x; x.i = ((unsigned int)u) << 16; return x.f;
}
static __device__ __forceinline__ unsigned short f2bf(float f) {
    union { float f; unsigned int i; } x; x.f = f;
    unsigned int r = x.i + 0x7FFFu + ((x.i >> 16) & 1u);
    return (unsigned short)(r >> 16);
}

static __device__ __forceinline__ void gload_lds16(const void* g, void* s) {
    __builtin_amdgcn_global_load_lds(
        (const __attribute__((address_space(1))) unsigned int*)g,
        (__attribute__((address_space(3))) unsigned int*)s, 16, 0, 0);
}

// ---------------- merged fp32 -> bf16 conversion (x, qkv_w, out_w) ---------
#define NX8  (M_TOK * DIMC / 8)          // 1048576
#define NWQ8 (N_QKV * DIMC / 8)          // 98304
#define NWO8 (DIMC * DIMC / 8)           // 32768
__global__ __launch_bounds__(256) void cvt_all(
    const float* __restrict__ x,  const float* __restrict__ wq,
    const float* __restrict__ wo, unsigned short* __restrict__ xb,
    unsigned short* __restrict__ wqb, unsigned short* __restrict__ wob)
{
    int i = blockIdx.x * 256 + threadIdx.x;
    const float* src; unsigned short* dst; int off;
    if (i < NX8)             { src = x;  dst = xb;  off = i; }
    else if (i < NX8 + NWQ8) { src = wq; dst = wqb; off = i - NX8; }
    else                     { src = wo; dst = wob; off = i - NX8 - NWQ8; }
    const float4* p = (const float4*)src + (size_t)off * 2;
    float4 a = p[0], b = p[1];
    u16v8 o;
    o[0] = f2bf(a.x); o[1] = f2bf(a.y); o[2] = f2bf(a.z); o[3] = f2bf(a.w);
    o[4] = f2bf(b.x); o[5] = f2bf(b.y); o[6] = f2bf(b.z); o[7] = f2bf(b.w);
    *(u16v8*)(dst + (size_t)off * 8) = o;
}

// ---- NT MFMA GEMM, 128x256 block, BK=32, RING-3 LDS + counted vmcnt -------
// C[M][N] = A[M][K]*B[N][K]^T + bias. 512 thr / 8 waves (2Mx4N), 64x64/wave.
// R13 change vs R12: REMOVED the forced lgkmcnt(0)+sched_barrier(0) before
// the MFMA cluster. ds_reads are plain C++ loads -> compiler emits counted
// lgkmcnt(4/3/1/0) between read and consuming MFMA (m97 pattern), letting the
// first MFMAs overlap the LDS read latency instead of serializing on a full
// drain every K-tile. Safety: MFMA<->read deps are register-carried; read
// slot (t%3) never aliases stage slot ((t+2)%3); cross-iter reuse guarded by
// VMCNT+s_barrier as before.
template<bool OUT_BF16>
__global__ __launch_bounds__(512) void gemm_nt_r3(
    const unsigned short* __restrict__ A,  // [M][K] bf16
    const unsigned short* __restrict__ B,  // [N][K] bf16
    const float* __restrict__ bias,        // [N]
    void* __restrict__ Cout,
    int M, int N, int K)
{
    __shared__ __align__(16) unsigned short As[3][128 * 32];   // 24KB
    __shared__ __align__(16) unsigned short Bs[3][256 * 32];   // 48KB
    const int tid  = threadIdx.x;
    const int lane = tid & 63;
    const int wid  = tid >> 6;       // 0..7
    const int wm   = wid >> 2;       // 0..1 -> rows [wm*64,+64)
    const int wn   = wid & 3;        // 0..3 -> cols [wn*64,+64)
    const int m0 = blockIdx.x * 128;
    const int n0 = blockIdx.y * 256;
    const int frow = lane & 15;
    const int fcol = (lane >> 4) * 8;
    const int NT = K >> 5;           // 16 K-tiles

    f32v4 acc[4][4] = {};

    // staging addresses (inverse-swizzled global source, rule 21)
    const int arow = tid >> 2;
    const int acol = ((tid & 3) * 8) ^ (((arow >> 1) & 3) << 3);
    const unsigned short* aSrc = A + (size_t)(m0 + arow) * K + acol;
    const unsigned short* bSrc[2];
    #pragma unroll
    for (int r = 0; r < 2; ++r) {
        const int brow = r * 128 + (tid >> 2);
        const int bcol = ((tid & 3) * 8) ^ (((brow >> 1) & 3) << 3);
        bSrc[r] = B + (size_t)(n0 + brow) * K + bcol;
    }
    const int aDst = wid * 512;            // wave-uniform (+lane*16B by HW)

#define STAGE(kt, slot)                                                        \
    {                                                                          \
        gload_lds16(aSrc + (kt) * 32, &As[slot][aDst]);                        \
        gload_lds16(bSrc[0] + (kt) * 32, &Bs[slot][aDst]);                     \
        gload_lds16(bSrc[1] + (kt) * 32, &Bs[slot][4096 + aDst]);              \
    }

    STAGE(0, 0)
    STAGE(1, 1)
    VMCNT(3);                      // tile-0 landed (only tile-1's 3 remain)
    __builtin_amdgcn_s_barrier();

    for (int t = 0; t < NT; ++t) {
        const int slot = t % 3;
        bfv8 af[4], bf[4];
        #pragma unroll
        for (int i = 0; i < 4; ++i) {
            const int r = wm * 64 + i * 16 + frow;
            af[i] = *(const bfv8*)(&As[slot][r * 32 + (fcol ^ (((r >> 1) & 3) << 3))]);
        }
        #pragma unroll
        for (int j = 0; j < 4; ++j) {
            const int r = wn * 64 + j * 16 + frow;
            bf[j] = *(const bfv8*)(&Bs[slot][r * 32 + (fcol ^ (((r >> 1) & 3) << 3))]);
        }
        if (t + 2 < NT) {
            const int ws = (t + 2) % 3;
            STAGE(t + 2, ws)
        }
        // no forced lgkm drain: compiler inserts counted lgkmcnt before each
        // consuming MFMA, overlapping read latency with the MFMA cluster.
        __builtin_amdgcn_s_setprio(1);
        #pragma unroll
        for (int i = 0; i < 4; ++i)
            #pragma unroll
            for (int j = 0; j < 4; ++j)
                acc[i][j] = __builtin_amdgcn_mfma_f32_16x16x32_bf16(
                    af[i], bf[j], acc[i][j], 0, 0, 0);
        __builtin_amdgcn_s_setprio(0);
        if (t + 2 < NT) { VMCNT(3); } else { VMCNT(0); }
        __builtin_amdgcn_s_barrier();
    }
#undef STAGE

    // epilogue: D row=(lane>>4)*4+r, col=lane&15 (m89-verified, R2..R12-proven)
    const int erow = (lane >> 4) * 4;
    const int ecol = lane & 15;
    #pragma unroll
    for (int j = 0; j < 4; ++j) {
        const int col = n0 + wn * 64 + j * 16 + ecol;
        const float bv = bias[col];
        #pragma unroll
        for (int i = 0; i < 4; ++i) {
            const int rbase = m0 + wm * 64 + i * 16 + erow;
            #pragma unroll
            for (int r = 0; r < 4; ++r) {
                const float v = acc[i][j][r] + bv;
                if constexpr (OUT_BF16)
                    ((unsigned short*)Cout)[(size_t)(rbase + r) * N + col] = f2bf(v);
                else
                    ((float*)Cout)[(size_t)(rbase + r) * N + col] = v;
            }
        }
    }
}

// ---------------- per-token 8x8 head-mix attention, LDS-free ----------------
// 16 lanes per token: lane16 = h*2 + half (half = 32-dim split).
// Writes Y2 scrambled: y[b][h*512 + (n>>3)][(n&7)*64 + d].
__global__ __launch_bounds__(256) void attn_mix2(
    const unsigned short* __restrict__ Y1, // [16384][1536] bf16
    unsigned short* __restrict__ Y2)       // [16384][512]  bf16 (scrambled)
{
    const int tid  = threadIdx.x;
    const int tok  = blockIdx.x * 16 + (tid >> 4);
    const int l16  = tid & 15;
    const int h    = l16 >> 1;
    const int half = l16 & 1;
    const unsigned short* qkv = Y1 + (size_t)tok * N_QKV;

    float qf[32];
    #pragma unroll
    for (int c = 0; c < 4; ++c) {
        u16v8 v = *(const u16v8*)(qkv + h * 64 + half * 32 + c * 8);
        #pragma unroll
        for (int j = 0; j < 8; ++j) qf[c * 8 + j] = bf2f(v[j]);
    }
    float sc[8];
    #pragma unroll
    for (int g = 0; g < 8; ++g) {
        const unsigned short* kp = qkv + DIMC + g * 64 + half * 32;
        float a = 0.f;
        #pragma unroll
        for (int c = 0; c < 4; ++c) {
            u16v8 v = *(const u16v8*)(kp + c * 8);
            #pragma unroll
            for (int j = 0; j < 8; ++j) a = fmaf(qf[c * 8 + j], bf2f(v[j]), a);
        }
        a += __shfl_xor(a, 1);       // combine the two 32-dim halves
        sc[g] = a * 0.125f;
    }
    float mx = sc[0];
    #pragma unroll
    for (int g = 1; g < 8; ++g) mx = fmaxf(mx, sc[g]);
    float sum = 0.f;
    #pragma unroll
    for (int g = 0; g < 8; ++g) { sc[g] = __expf(sc[g] - mx); sum += sc[g]; }
    const float inv = 1.f / sum;
    #pragma unroll
    for (int g = 0; g < 8; ++g) sc[g] *= inv;

    float o[32] = {};
    #pragma unroll
    for (int g = 0; g < 8; ++g) {
        const unsigned short* vp = qkv + 2 * DIMC + g * 64 + half * 32;
        #pragma unroll
        for (int c = 0; c < 4; ++c) {
            u16v8 v = *(const u16v8*)(vp + c * 8);
            #pragma unroll
            for (int j = 0; j < 8; ++j) o[c * 8 + j] = fmaf(sc[g], bf2f(v[j]), o[c * 8 + j]);
        }
    }
    const int n = tok & (SEQ - 1);
    const int b = tok >> 12;
    const size_t drow = (size_t)b * SEQ + h * 512 + (n >> 3);
    unsigned short* dst = Y2 + drow * DIMC + ((n & 7) << 6) + half * 32;
    #pragma unroll
    for (int c = 0; c < 4; ++c) {
        u16v8 ov;
        #pragma unroll
        for (int j = 0; j < 8; ++j) ov[j] = f2bf(o[c * 8 + j]);
        *(u16v8*)(dst + c * 8) = ov;
    }
}

extern "C" void kernel_launch(void* const* d_in, const int* in_sizes, int n_in,
                              void* d_out, int out_size, void* d_ws, size_t ws_size,
                              hipStream_t stream) {
    const float* x     = (const float*)d_in[0];
    const float* qkv_w = (const float*)d_in[1];
    const float* qkv_b = (const float*)d_in[2];
    const float* out_w = (const float*)d_in[3];
    const float* out_b = (const float*)d_in[4];
    float* out = (float*)d_out;

    unsigned short* Y1 = (unsigned short*)d_ws;            // 50.3 MB
    unsigned short* Xb = Y1 + (size_t)M_TOK * N_QKV;       // 16.8 MB
    unsigned short* Y2 = Xb;   // overlay: Xb dead before attn_mix2 writes Y2
    unsigned short* Wq = Xb + (size_t)M_TOK * DIMC;
    unsigned short* Wo = Wq + (size_t)N_QKV * DIMC;

    cvt_all<<<(NX8 + NWQ8 + NWO8) / 256, 256, 0, stream>>>(x, qkv_w, out_w, Xb, Wq, Wo);

    gemm_nt_r3<true><<<dim3(M_TOK / 128, N_QKV / 256), 512, 0, stream>>>(
        Xb, Wq, qkv_b, Y1, M_TOK, N_QKV, DIMC);

    attn_mix2<<<M_TOK / 16, 256, 0, stream>>>(Y1, Y2);

    gemm_nt_r3<false><<<dim3(M_TOK / 128, DIMC / 256), 512, 0, stream>>>(
        Y2, Wo, out_b, out, M_TOK, DIMC, DIMC);
}